// Round 9
// baseline (198.596 us; speedup 1.0000x reference)
//
#include <hip/hip_runtime.h>
#include <math.h>

#define N_NODES 50000
#define N_EDGES 1600000
#define IN_F 256
#define HID 128
#define NCLS 40
#define HS2 40        // f16 row stride for 40-wide tables (80 B exact; table = 4.0 MB)
#define NP 50048      // padded node count (ws layout)
#define NBINS 196     // ceil(50000/256) coarse bins of 256 nodes
#define MS_BLOCKS 200
#define MS_CHUNK 8000 // MS_BLOCKS * MS_CHUNK == N_EDGES
#define BIN_CAP 12288 // bin region capacity; mean fill 8192, sigma ~91 -> 45-sigma headroom
#define GEMM_BLOCKS 782  // (N_NODES + 63) / 64

typedef __attribute__((ext_vector_type(8))) short short8;     // 8 bf16 (4 VGPRs)
typedef __attribute__((ext_vector_type(4))) float v4f;        // MFMA acc
typedef __attribute__((ext_vector_type(2))) _Float16 h2v;     // packed f16 pair

__device__ __forceinline__ unsigned short f2bf(float f) {
    union { float f; unsigned int i; } v;
    v.f = f;
    unsigned int r = v.i + 0x7FFF + ((v.i >> 16) & 1);  // RNE
    return (unsigned short)(r >> 16);
}
__device__ __forceinline__ h2v u2h(unsigned int u) {
    union { unsigned int i; h2v h; } v; v.i = u; return v.h;
}
__device__ __forceinline__ unsigned int h2u(h2v h) {
    union { h2v h; unsigned int i; } v; v.h = h; return v.i;
}

// ---------------- init bin cursors to static over-allocated bases -------------

__global__ __launch_bounds__(256) void k_init(int* __restrict__ cur_d,
                                              int* __restrict__ cur_s) {
    int t = threadIdx.x;
    if (t < NBINS) {
        cur_d[t] = t * BIN_CAP;
        cur_s[t] = t * BIN_CAP;
    }
}

// -------- fused: dst/src multisplit (0..399) + W12 fragments (400..405) + b1w2
// blocks [0,200): key=dst, payload (dstlow<<16|src) -> binned_d
// blocks [200,400): key=src, payload srclow byte -> binned_s (degree counts only)
// Stage arrays split ushort+uchar: 35KB LDS -> 4 blocks/CU (was 44KB -> 3).
// deg counting stays SORT-BASED: round-6 measured 1.6M scattered global
// atomicAdds at 78us (50MB HBM write amplification, per-line serialization).

__global__ __launch_bounds__(256) void k_ms(const int* __restrict__ src,
                                            const int* __restrict__ dst,
                                            int* __restrict__ cur_d, int* __restrict__ cur_s,
                                            int* __restrict__ binned_d,
                                            unsigned char* __restrict__ binned_s,
                                            const float* __restrict__ W1,
                                            const float* __restrict__ b1,
                                            const float* __restrict__ W2,
                                            short* __restrict__ w12f,
                                            float* __restrict__ b1w2) {
    __shared__ int smem[9024];   // 36KB carve-out; W12 path aliases first 20KB
    int t = threadIdx.x;
    if (blockIdx.x < 2 * MS_BLOCKS) {
        int* hist  = smem;                                     // 256
        int* delta = smem + 256;                               // 256
        int* lcur  = smem + 512;                               // 256
        int* sm    = smem + 768;                               // 256
        unsigned short* stage_s = (unsigned short*)(smem + 1024);  // 8000 ushort (16KB)
        unsigned char*  stage_b = (unsigned char*)(smem + 5024);   // 8000 B
        unsigned char*  binof   = (unsigned char*)(smem + 7024);   // 8000 B
        int side = blockIdx.x / MS_BLOCKS;
        int e0 = (blockIdx.x % MS_BLOCKS) * MS_CHUNK;
        const int* key = side ? src : dst;
        for (int i = t; i < NBINS; i += 256) hist[i] = 0;
        __syncthreads();
        for (int i = t; i < MS_CHUNK; i += 256) atomicAdd(&hist[key[e0 + i] >> 8], 1);
        __syncthreads();
        int hv = (t < NBINS) ? hist[t] : 0;
        sm[t] = hv;
        __syncthreads();
        for (int off = 1; off < 256; off <<= 1) {
            int a = (t >= off) ? sm[t - off] : 0;
            __syncthreads();
            sm[t] += a;
            __syncthreads();
        }
        if (t < NBINS) {
            int ex = sm[t] - hv;
            // reserve hv slots in this bin's region (45-sigma overflow headroom)
            int g = atomicAdd(side ? &cur_s[t] : &cur_d[t], hv);
            delta[t] = g - ex;
            lcur[t] = ex;
        }
        __syncthreads();
        if (side == 0) {
            for (int i = t; i < MS_CHUNK; i += 256) {
                int kf = key[e0 + i];
                int v = src[e0 + i];
                int b = kf >> 8;
                int pos = atomicAdd(&lcur[b], 1);
                stage_s[pos] = (unsigned short)v;          // src < 2^16
                stage_b[pos] = (unsigned char)(kf & 255);  // dstlow
                binof[pos] = (unsigned char)b;
            }
            __syncthreads();
            for (int i = t; i < MS_CHUNK; i += 256)
                binned_d[i + delta[binof[i]]] = ((int)stage_b[i] << 16) | (int)stage_s[i];
        } else {
            for (int i = t; i < MS_CHUNK; i += 256) {
                int kf = key[e0 + i];
                int b = kf >> 8;
                int pos = atomicAdd(&lcur[b], 1);
                stage_b[pos] = (unsigned char)(kf & 255);  // srclow
                binof[pos] = (unsigned char)b;
            }
            __syncthreads();
            for (int i = t; i < MS_CHUNK; i += 256)
                binned_s[i + delta[binof[i]]] = stage_b[i];
        }
        return;
    }
    if (blockIdx.x == 2 * MS_BLOCKS + 6) {
        int c = t;
        if (c < NCLS) {
            float a0 = 0.f, a1 = 0.f, a2 = 0.f, a3 = 0.f;   // 4 chains for ILP
            for (int k = 0; k < HID; k += 4) {
                a0 += b1[k + 0] * W2[(k + 0) * NCLS + c];
                a1 += b1[k + 1] * W2[(k + 1) * NCLS + c];
                a2 += b1[k + 2] * W2[(k + 2) * NCLS + c];
                a3 += b1[k + 3] * W2[(k + 3) * NCLS + c];
            }
            b1w2[c] = (a0 + a1) + (a2 + a3);
        }
        return;
    }
    // W12 = W1@W2 fragment blocks (LDS-staged W2, float4 W1, 8 acc chains)
    float* w2s = (float*)smem;
    for (int i = t; i < HID * NCLS; i += 256) w2s[i] = W2[i];
    __syncthreads();
    int g = (blockIdx.x - 2 * MS_BLOCKS) * 256 + t;   // slot id in [0,1536)
    int kt = g / 192, rem = g % 192;
    int nt = rem >> 6, lane = rem & 63;
    int q = lane >> 4, n = lane & 15;
    int col = nt * 16 + n;
    float acc[8];
#pragma unroll
    for (int j = 0; j < 8; j++) acc[j] = 0.f;
    if (col < NCLS) {
        int k0 = kt * 32 + q * 8;
        const float* w1r = &W1[(size_t)k0 * HID];   // 8 consecutive rows, 16-lane shared
        for (int jj = 0; jj < HID; jj += 4) {
            float w0 = w2s[(jj + 0) * NCLS + col];
            float w1v = w2s[(jj + 1) * NCLS + col];
            float w2v = w2s[(jj + 2) * NCLS + col];
            float w3 = w2s[(jj + 3) * NCLS + col];
#pragma unroll
            for (int j = 0; j < 8; j++) {
                float4 a = *(const float4*)&w1r[j * HID + jj];
                acc[j] += a.x * w0 + a.y * w1v + a.z * w2v + a.w * w3;
            }
        }
    }
    short8 v;
#pragma unroll
    for (int j = 0; j < 8; j++) v[j] = (short)f2bf(acc[j]);
    *(short8*)&w12f[(size_t)g * 8] = v;
}

// ---------------- dout from src-bin counts (small, unblocks gemm1) ------------

__global__ __launch_bounds__(256) void k_dout(const unsigned char* __restrict__ binned_s,
                                              const int* __restrict__ cur_s,
                                              float* __restrict__ dout) {
    __shared__ int hist[256];
    int t = threadIdx.x;
    hist[t] = 0;
    __syncthreads();
    int bin = blockIdx.x;
    int beg = bin * BIN_CAP;
    int n = cur_s[bin] - beg;
    for (int i = t; i < n; i += 256) atomicAdd(&hist[binned_s[beg + i]], 1);
    __syncthreads();
    int node = bin * 256 + t;
    if (node < N_NODES) {
        int hv = hist[t];
        dout[node] = hv ? rsqrtf((float)hv) : 0.f;
    }
}

// ------- fused: dst-bin counting sort (blocks 0..195) + GEMM1 (196..977) ------
// The two halves are independent (gemm1 needs only dout, ready from k_dout);
// fusing overlaps the LDS-bound sort with the HBM-streaming MFMA GEMM.
// ushort stage -> 27KB LDS -> 5 blocks/CU for the gemm blocks.

__global__ __launch_bounds__(256) void k_sg(const int* __restrict__ binned_d,
                                            const int* __restrict__ cur_d,
                                            int* __restrict__ offsets, float* __restrict__ din,
                                            unsigned short* __restrict__ deg16,
                                            unsigned short* __restrict__ csr16,
                                            const float* __restrict__ x,
                                            const short* __restrict__ w12f,
                                            const float* __restrict__ dout,
                                            _Float16* __restrict__ gt) {
    __shared__ int hist[256];
    __shared__ int sm[256];
    __shared__ int cur[256];
    __shared__ unsigned short stage16[BIN_CAP];   // 24KB
    int t = threadIdx.x;
    if (blockIdx.x < NBINS) {
        hist[t] = 0;
        __syncthreads();
        int bin = blockIdx.x;
        int beg = bin * BIN_CAP;
        int n = cur_d[bin] - beg;       // actual fill of this bin region
        for (int i = t; i < n; i += 256) atomicAdd(&hist[binned_d[beg + i] >> 16], 1);
        __syncthreads();
        int hv = hist[t];
        sm[t] = hv;
        __syncthreads();
        for (int off = 1; off < 256; off <<= 1) {
            int a = (t >= off) ? sm[t - off] : 0;
            __syncthreads();
            sm[t] += a;
            __syncthreads();
        }
        int ex = sm[t] - hv;
        int node = bin * 256 + t;
        if (node < N_NODES) {
            offsets[node] = beg + ex;           // index into gapped csr16
            deg16[node] = (unsigned short)hv;   // gapped layout: offsets[n+1] invalid
            din[node] = hv ? rsqrtf((float)hv) : 0.f;
        }
        cur[t] = ex;
        __syncthreads();
        for (int i = t; i < n; i += 256) {
            int p = binned_d[beg + i];
            int pos = atomicAdd(&cur[p >> 16], 1);
            if (pos < BIN_CAP) stage16[pos] = (unsigned short)(p & 0xFFFF);
        }
        __syncthreads();
        int m = n < BIN_CAP ? n : BIN_CAP;
        int mw = (m + 1) >> 1;                  // vectorized uint writes
        unsigned int* dp = (unsigned int*)&csr16[beg];
        const unsigned int* sp = (const unsigned int*)stage16;
        for (int i = t; i < mw; i += 256) dp[i] = sp[i];
        return;
    }
    // ---- GEMM1: g = (x @ W12) * dout[row], 40-wide ----
    int wv = t >> 6, lane = t & 63;
    int q = lane >> 4, lr = lane & 15;
    int m0 = (blockIdx.x - NBINS) * 64 + wv * 16;
    int row = m0 + lr;
    int rowc = min(row, N_NODES - 1);      // clamp: tail rows read row 49999, stores guarded
    v4f acc[3];
#pragma unroll
    for (int n = 0; n < 3; n++) acc[n] = (v4f){0.f, 0.f, 0.f, 0.f};

    const float* xr = &x[(size_t)rowc * IN_F];
#pragma unroll
    for (int kt = 0; kt < 8; kt++) {
        const float4* ap = (const float4*)&xr[kt * 32 + q * 8];
        float4 a0 = ap[0], a1 = ap[1];
        short8 af;
        af[0] = (short)f2bf(a0.x); af[1] = (short)f2bf(a0.y);
        af[2] = (short)f2bf(a0.z); af[3] = (short)f2bf(a0.w);
        af[4] = (short)f2bf(a1.x); af[5] = (short)f2bf(a1.y);
        af[6] = (short)f2bf(a1.z); af[7] = (short)f2bf(a1.w);
#pragma unroll
        for (int nt = 0; nt < 3; nt++) {
            short8 bf = *(const short8*)&w12f[(size_t)((kt * 3 + nt) * 64 + lane) * 8];
            acc[nt] = __builtin_amdgcn_mfma_f32_16x16x32_bf16(af, bf, acc[nt], 0, 0, 0);
        }
    }
    int rbase = m0 + q * 4;
    float4 dv = *(const float4*)&dout[rbase];   // dout is NP-padded, OOB-safe
#pragma unroll
    for (int i = 0; i < 4; i++) {
        int orow = rbase + i;
        if (orow < N_NODES) {
            float s = (i == 0) ? dv.x : (i == 1) ? dv.y : (i == 2) ? dv.z : dv.w;
#pragma unroll
            for (int nt = 0; nt < 3; nt++) {
                int col = nt * 16 + lr;
                if (col < NCLS)
                    gt[(size_t)orow * HS2 + col] = (_Float16)(acc[nt][i] * s);
            }
        }
    }
}

// ---------------- Aggregation 1 (40-wide, dual-half) --------------------------
// Two adjacent dst nodes per wave: lanes 0-31 serve node0, 32-63 node1.
// Ends come from deg16 (gapped csr16 regions); wid0 even -> one uint load
// covers both degrees.

__global__ __launch_bounds__(256) void k_agg1b(const unsigned short* __restrict__ csr16,
                                               const int* __restrict__ offsets,
                                               const unsigned short* __restrict__ deg16,
                                               const _Float16* __restrict__ g,
                                               const float* __restrict__ din,
                                               const float* __restrict__ dout,
                                               const float* __restrict__ b1w2,
                                               _Float16* __restrict__ h2b) {
    int w = (int)((blockIdx.x * 256 + threadIdx.x) >> 6);
    int wid0 = w * 2;
    if (wid0 >= N_NODES) return;
    int wid1 = wid0 + 1;                  // N even -> always valid
    int lane = threadIdx.x & 63;
    int half = lane >> 5;
    int hl = lane & 31;
    int grp = hl >> 3;                    // 4 edge groups per half
    int l = hl & 7;
    bool act = l < 5;                     // 5 lanes x 8 cols = 40
    int colb = min(l, 4) * 8;
    int sbase = half << 5;
    int beg0 = offsets[wid0];
    int beg1 = offsets[wid1];
    unsigned int dp = *(const unsigned int*)&deg16[wid0];
    int end0 = beg0 + (int)(dp & 0xFFFFu);
    int end1 = beg1 + (int)(dp >> 16);
    int myend = half ? end1 : end0;
    h2v a0 = (h2v)0, a1 = (h2v)0, a2 = (h2v)0, a3 = (h2v)0;
    for (int base0 = beg0, base1 = beg1; base0 < end0 || base1 < end1;
         base0 += 32, base1 += 32) {
        int mybase = half ? base1 : base0;
        int idx = mybase + hl;
        int sv = (idx < myend) ? (int)csr16[idx] : 0;
        int mycnt = min(32, myend - mybase);    // uniform per half; may be <= 0
        int mycl = max(mycnt - 1, 0);
        int e0 = grp * 8 + 0, e1 = grp * 8 + 1, e2 = grp * 8 + 2, e3 = grp * 8 + 3;
        int e4 = grp * 8 + 4, e5 = grp * 8 + 5, e6 = grp * 8 + 6, e7 = grp * 8 + 7;
        int s0 = __shfl(sv, sbase + min(e0, mycl));
        int s1 = __shfl(sv, sbase + min(e1, mycl));
        int s2 = __shfl(sv, sbase + min(e2, mycl));
        int s3 = __shfl(sv, sbase + min(e3, mycl));
        int s4 = __shfl(sv, sbase + min(e4, mycl));
        int s5 = __shfl(sv, sbase + min(e5, mycl));
        int s6 = __shfl(sv, sbase + min(e6, mycl));
        int s7 = __shfl(sv, sbase + min(e7, mycl));
        if (act && mycnt > 0) {
            uint4 v0 = *(const uint4*)&g[(size_t)s0 * HS2 + colb];
            uint4 v1 = *(const uint4*)&g[(size_t)s1 * HS2 + colb];
            uint4 v2 = *(const uint4*)&g[(size_t)s2 * HS2 + colb];
            uint4 v3 = *(const uint4*)&g[(size_t)s3 * HS2 + colb];
            uint4 v4 = *(const uint4*)&g[(size_t)s4 * HS2 + colb];
            uint4 v5 = *(const uint4*)&g[(size_t)s5 * HS2 + colb];
            uint4 v6 = *(const uint4*)&g[(size_t)s6 * HS2 + colb];
            uint4 v7 = *(const uint4*)&g[(size_t)s7 * HS2 + colb];
            if (e0 < mycnt) { a0 += u2h(v0.x); a1 += u2h(v0.y); a2 += u2h(v0.z); a3 += u2h(v0.w); }
            if (e1 < mycnt) { a0 += u2h(v1.x); a1 += u2h(v1.y); a2 += u2h(v1.z); a3 += u2h(v1.w); }
            if (e2 < mycnt) { a0 += u2h(v2.x); a1 += u2h(v2.y); a2 += u2h(v2.z); a3 += u2h(v2.w); }
            if (e3 < mycnt) { a0 += u2h(v3.x); a1 += u2h(v3.y); a2 += u2h(v3.z); a3 += u2h(v3.w); }
            if (e4 < mycnt) { a0 += u2h(v4.x); a1 += u2h(v4.y); a2 += u2h(v4.z); a3 += u2h(v4.w); }
            if (e5 < mycnt) { a0 += u2h(v5.x); a1 += u2h(v5.y); a2 += u2h(v5.z); a3 += u2h(v5.w); }
            if (e6 < mycnt) { a0 += u2h(v6.x); a1 += u2h(v6.y); a2 += u2h(v6.z); a3 += u2h(v6.w); }
            if (e7 < mycnt) { a0 += u2h(v7.x); a1 += u2h(v7.y); a2 += u2h(v7.z); a3 += u2h(v7.w); }
        }
    }
    float c[8];
    c[0] = (float)a0[0]; c[1] = (float)a0[1];
    c[2] = (float)a1[0]; c[3] = (float)a1[1];
    c[4] = (float)a2[0]; c[5] = (float)a2[1];
    c[6] = (float)a3[0]; c[7] = (float)a3[1];
#pragma unroll
    for (int i = 0; i < 8; i++) {           // reduce over 4 groups WITHIN half
        c[i] += __shfl_xor(c[i], 8);
        c[i] += __shfl_xor(c[i], 16);
    }
    if (grp == 0 && act) {
        int wid = half ? wid1 : wid0;
        float dd = dout[wid];
        float sc = din[wid] * dd;
        float4 bw0 = *(const float4*)&b1w2[colb];
        float4 bw1 = *(const float4*)&b1w2[colb + 4];
        h2v p0, p1, p2, p3;
        p0[0] = (_Float16)(c[0] * sc + bw0.x * dd); p0[1] = (_Float16)(c[1] * sc + bw0.y * dd);
        p1[0] = (_Float16)(c[2] * sc + bw0.z * dd); p1[1] = (_Float16)(c[3] * sc + bw0.w * dd);
        p2[0] = (_Float16)(c[4] * sc + bw1.x * dd); p2[1] = (_Float16)(c[5] * sc + bw1.y * dd);
        p3[0] = (_Float16)(c[6] * sc + bw1.z * dd); p3[1] = (_Float16)(c[7] * sc + bw1.w * dd);
        uint4 o;
        o.x = h2u(p0); o.y = h2u(p1); o.z = h2u(p2); o.w = h2u(p3);
        *(uint4*)&h2b[(size_t)wid * HS2 + colb] = o;
    }
}

// ---------------- Aggregation 2 + bias + log_softmax (dual-half) --------------

__global__ __launch_bounds__(256) void k_agg2(const unsigned short* __restrict__ csr16,
                                              const int* __restrict__ offsets,
                                              const unsigned short* __restrict__ deg16,
                                              const _Float16* __restrict__ h2b,
                                              const float* __restrict__ din,
                                              const float* __restrict__ b2,
                                              float* __restrict__ out) {
    int w = (int)((blockIdx.x * 256 + threadIdx.x) >> 6);
    int wid0 = w * 2;
    if (wid0 >= N_NODES) return;
    int wid1 = wid0 + 1;
    int lane = threadIdx.x & 63;
    int half = lane >> 5;
    int hl = lane & 31;
    int grp = hl >> 3;
    int l = hl & 7;
    bool act = l < 5;
    int colb = min(l, 4) * 8;
    int sbase = half << 5;
    int beg0 = offsets[wid0];
    int beg1 = offsets[wid1];
    unsigned int dp = *(const unsigned int*)&deg16[wid0];
    int end0 = beg0 + (int)(dp & 0xFFFFu);
    int end1 = beg1 + (int)(dp >> 16);
    int myend = half ? end1 : end0;
    h2v a0 = (h2v)0, a1 = (h2v)0, a2 = (h2v)0, a3 = (h2v)0;
    for (int base0 = beg0, base1 = beg1; base0 < end0 || base1 < end1;
         base0 += 32, base1 += 32) {
        int mybase = half ? base1 : base0;
        int idx = mybase + hl;
        int sv = (idx < myend) ? (int)csr16[idx] : 0;
        int mycnt = min(32, myend - mybase);
        int mycl = max(mycnt - 1, 0);
        int e0 = grp * 8 + 0, e1 = grp * 8 + 1, e2 = grp * 8 + 2, e3 = grp * 8 + 3;
        int e4 = grp * 8 + 4, e5 = grp * 8 + 5, e6 = grp * 8 + 6, e7 = grp * 8 + 7;
        int s0 = __shfl(sv, sbase + min(e0, mycl));
        int s1 = __shfl(sv, sbase + min(e1, mycl));
        int s2 = __shfl(sv, sbase + min(e2, mycl));
        int s3 = __shfl(sv, sbase + min(e3, mycl));
        int s4 = __shfl(sv, sbase + min(e4, mycl));
        int s5 = __shfl(sv, sbase + min(e5, mycl));
        int s6 = __shfl(sv, sbase + min(e6, mycl));
        int s7 = __shfl(sv, sbase + min(e7, mycl));
        if (act && mycnt > 0) {
            uint4 v0 = *(const uint4*)&h2b[(size_t)s0 * HS2 + colb];
            uint4 v1 = *(const uint4*)&h2b[(size_t)s1 * HS2 + colb];
            uint4 v2 = *(const uint4*)&h2b[(size_t)s2 * HS2 + colb];
            uint4 v3 = *(const uint4*)&h2b[(size_t)s3 * HS2 + colb];
            uint4 v4 = *(const uint4*)&h2b[(size_t)s4 * HS2 + colb];
            uint4 v5 = *(const uint4*)&h2b[(size_t)s5 * HS2 + colb];
            uint4 v6 = *(const uint4*)&h2b[(size_t)s6 * HS2 + colb];
            uint4 v7 = *(const uint4*)&h2b[(size_t)s7 * HS2 + colb];
            if (e0 < mycnt) { a0 += u2h(v0.x); a1 += u2h(v0.y); a2 += u2h(v0.z); a3 += u2h(v0.w); }
            if (e1 < mycnt) { a0 += u2h(v1.x); a1 += u2h(v1.y); a2 += u2h(v1.z); a3 += u2h(v1.w); }
            if (e2 < mycnt) { a0 += u2h(v2.x); a1 += u2h(v2.y); a2 += u2h(v2.z); a3 += u2h(v2.w); }
            if (e3 < mycnt) { a0 += u2h(v3.x); a1 += u2h(v3.y); a2 += u2h(v3.z); a3 += u2h(v3.w); }
            if (e4 < mycnt) { a0 += u2h(v4.x); a1 += u2h(v4.y); a2 += u2h(v4.z); a3 += u2h(v4.w); }
            if (e5 < mycnt) { a0 += u2h(v5.x); a1 += u2h(v5.y); a2 += u2h(v5.z); a3 += u2h(v5.w); }
            if (e6 < mycnt) { a0 += u2h(v6.x); a1 += u2h(v6.y); a2 += u2h(v6.z); a3 += u2h(v6.w); }
            if (e7 < mycnt) { a0 += u2h(v7.x); a1 += u2h(v7.y); a2 += u2h(v7.z); a3 += u2h(v7.w); }
        }
    }
    float c[8];
    c[0] = (float)a0[0]; c[1] = (float)a0[1];
    c[2] = (float)a1[0]; c[3] = (float)a1[1];
    c[4] = (float)a2[0]; c[5] = (float)a2[1];
    c[6] = (float)a3[0]; c[7] = (float)a3[1];
#pragma unroll
    for (int i = 0; i < 8; i++) {           // reduce over 4 groups WITHIN half
        c[i] += __shfl_xor(c[i], 8);
        c[i] += __shfl_xor(c[i], 16);
    }
    int wid = half ? wid1 : wid0;
    float sc = din[wid];
    float y[8];
    float lm = -INFINITY;
    if (act) {
        float4 bb0 = *(const float4*)&b2[colb];
        float4 bb1 = *(const float4*)&b2[colb + 4];
        y[0] = c[0] * sc + bb0.x; y[1] = c[1] * sc + bb0.y;
        y[2] = c[2] * sc + bb0.z; y[3] = c[3] * sc + bb0.w;
        y[4] = c[4] * sc + bb1.x; y[5] = c[5] * sc + bb1.y;
        y[6] = c[6] * sc + bb1.z; y[7] = c[7] * sc + bb1.w;
#pragma unroll
        for (int i = 0; i < 8; i++) lm = fmaxf(lm, y[i]);
    }
#pragma unroll
    for (int off = 1; off < 8; off <<= 1) lm = fmaxf(lm, __shfl_xor(lm, off));
    float ls = 0.f;
    if (act) {
#pragma unroll
        for (int i = 0; i < 8; i++) ls += expf(y[i] - lm);
    }
#pragma unroll
    for (int off = 1; off < 8; off <<= 1) ls += __shfl_xor(ls, off);
    if (grp == 0 && act) {
        float lg = logf(ls);
        float4 o0 = make_float4(y[0] - lm - lg, y[1] - lm - lg, y[2] - lm - lg, y[3] - lm - lg);
        float4 o1 = make_float4(y[4] - lm - lg, y[5] - lm - lg, y[6] - lm - lg, y[7] - lm - lg);
        *(float4*)&out[(size_t)wid * NCLS + colb] = o0;
        *(float4*)&out[(size_t)wid * NCLS + colb + 4] = o1;
    }
}

// ---------------- launch ----------------

extern "C" void kernel_launch(void* const* d_in, const int* in_sizes, int n_in,
                              void* d_out, int out_size, void* d_ws, size_t ws_size,
                              hipStream_t stream) {
    const float* x  = (const float*)d_in[0];
    const int* src  = (const int*)d_in[1];
    const int* dst  = (const int*)d_in[2];
    const float* W1 = (const float*)d_in[3];
    const float* b1 = (const float*)d_in[4];
    const float* W2 = (const float*)d_in[5];
    const float* b2 = (const float*)d_in[6];
    float* out = (float*)d_out;

    int* wsi   = (int*)d_ws;
    float* wsf = (float*)d_ws;
    const size_t BINREG = (size_t)NBINS * BIN_CAP;   // 2,408,448 entries per side
    // workspace layout (4B units):
    int* cur_d    = wsi;                      // 256
    int* cur_s    = wsi + 256;                // 256
    float* b1w2   = wsf + 512;                // 40 floats
    int* offsets  = wsi + 1536;               // NP
    float* din    = wsf + 1536 + (size_t)NP;      // NP
    float* dout   = wsf + 1536 + 2 * (size_t)NP;  // NP
    unsigned short* deg16 = (unsigned short*)(wsi + 1536 + 3 * (size_t)NP);  // NP ushorts
    int* binned_d = wsi + 1536 + 3 * (size_t)NP + NP / 2;   // BINREG ints (9.6 MB)
    unsigned char* binned_s = (unsigned char*)(binned_d + BINREG);           // BINREG bytes
    _Float16* gt  = (_Float16*)(binned_s + BINREG);                          // N*HS2 f16 (4.0 MB)
    _Float16* h2b = gt + (size_t)N_NODES * HS2;                              // N*HS2 f16 (4.0 MB)
    short* w12f   = (short*)(h2b + (size_t)N_NODES * HS2);                   // 12288 bf16 (24 KB)
    unsigned short* csr16 = (unsigned short*)(w12f + 12288);                 // BINREG ushorts (4.8 MB)

    k_init<<<1, 256, 0, stream>>>(cur_d, cur_s);
    k_ms<<<2 * MS_BLOCKS + 7, 256, 0, stream>>>(src, dst, cur_d, cur_s, binned_d, binned_s,
                                                W1, b1, W2, w12f, b1w2);
    k_dout<<<NBINS, 256, 0, stream>>>(binned_s, cur_s, dout);
    k_sg<<<NBINS + GEMM_BLOCKS, 256, 0, stream>>>(binned_d, cur_d, offsets, din, deg16, csr16,
                                                  x, w12f, dout, gt);
    k_agg1b<<<(N_NODES / 2) * 64 / 256, 256, 0, stream>>>(csr16, offsets, deg16, gt, din, dout, b1w2, h2b);
    k_agg2<<<(N_NODES / 2) * 64 / 256, 256, 0, stream>>>(csr16, offsets, deg16, h2b, din, b2, out);
}

// Round 10
// 191.865 us; speedup vs baseline: 1.0351x; 1.0351x over previous
//
#include <hip/hip_runtime.h>
#include <math.h>

#define N_NODES 50000
#define N_EDGES 1600000
#define IN_F 256
#define HID 128
#define NCLS 40
#define HS2 40        // f16 row stride for 40-wide tables (80 B exact; table = 4.0 MB)
#define NP 50048      // padded node count (ws layout)
#define NBINS 196     // ceil(50000/256) coarse bins of 256 nodes
#define MS_BLOCKS 200
#define MS_CHUNK 8000 // MS_BLOCKS * MS_CHUNK == N_EDGES
#define BIN_CAP 12288 // bin region capacity; mean fill 8192, sigma ~91 -> 45-sigma headroom

typedef __attribute__((ext_vector_type(8))) short short8;     // 8 bf16 (4 VGPRs)
typedef __attribute__((ext_vector_type(4))) float v4f;        // MFMA acc
typedef __attribute__((ext_vector_type(2))) _Float16 h2v;     // packed f16 pair

__device__ __forceinline__ unsigned short f2bf(float f) {
    union { float f; unsigned int i; } v;
    v.f = f;
    unsigned int r = v.i + 0x7FFF + ((v.i >> 16) & 1);  // RNE
    return (unsigned short)(r >> 16);
}
__device__ __forceinline__ h2v u2h(unsigned int u) {
    union { unsigned int i; h2v h; } v; v.i = u; return v.h;
}
__device__ __forceinline__ unsigned int h2u(h2v h) {
    union { h2v h; unsigned int i; } v; v.h = h; return v.i;
}

// ---------------- init bin cursors to static over-allocated bases -------------
// No bincount pass needed: bins are over-allocated (BIN_CAP = 45 sigma), blocks
// reserve space with one atomicAdd per bin. Deletes a full 12.8MB edge read.

__global__ __launch_bounds__(256) void k_init(int* __restrict__ cur_d,
                                              int* __restrict__ cur_s) {
    int t = threadIdx.x;
    if (t < NBINS) {
        cur_d[t] = t * BIN_CAP;
        cur_s[t] = t * BIN_CAP;
    }
}

// -------- fused: dst/src multisplit (0..399) + W12 fragments (400..405) + b1w2
// blocks [0,200): key=dst, payload (dstlow<<16|src) -> binned_d
// blocks [200,400): key=src, payload srclow byte -> binned_s (degree counts only)
// W12 = W1@W2 (256x40 pad 48) packed into gemm1 B-fragment layout (LDS-staged
// W2, float4 W1 reads, 8 acc chains -- the scalar version was a 40us latency
// chain). deg counting stays SORT-BASED: round-6 measured 1.6M scattered global
// atomicAdds at 78us (50MB HBM write amplification, per-line serialization).
// NOTE round-9 lesson: int stage (this version) beats ushort+uchar split stage;
// and fusing the dst-sort with gemm1 regressed (+4us) -- keep launches separate.

__global__ __launch_bounds__(256) void k_ms(const int* __restrict__ src,
                                            const int* __restrict__ dst,
                                            int* __restrict__ cur_d, int* __restrict__ cur_s,
                                            int* __restrict__ binned_d,
                                            unsigned char* __restrict__ binned_s,
                                            const float* __restrict__ W1,
                                            const float* __restrict__ b1,
                                            const float* __restrict__ W2,
                                            short* __restrict__ w12f,
                                            float* __restrict__ b1w2) {
    __shared__ int smem[11024];   // 44KB: multisplit carve-out / 20KB W12 stage
    int t = threadIdx.x;
    if (blockIdx.x < 2 * MS_BLOCKS) {
        int* hist  = smem;                                   // 256 slots (196 used)
        int* delta = smem + 256;
        int* lcur  = smem + 512;
        int* sm    = smem + 768;                             // 256
        int* stage = smem + 1024;                            // 8000 ints
        unsigned char* binof = (unsigned char*)(smem + 9024); // 8000 bytes
        int side = blockIdx.x / MS_BLOCKS;
        int e0 = (blockIdx.x % MS_BLOCKS) * MS_CHUNK;
        const int* key = side ? src : dst;
        for (int i = t; i < NBINS; i += 256) hist[i] = 0;
        __syncthreads();
        for (int i = t; i < MS_CHUNK; i += 256) atomicAdd(&hist[key[e0 + i] >> 8], 1);
        __syncthreads();
        int hv = (t < NBINS) ? hist[t] : 0;
        sm[t] = hv;
        __syncthreads();
        for (int off = 1; off < 256; off <<= 1) {
            int a = (t >= off) ? sm[t - off] : 0;
            __syncthreads();
            sm[t] += a;
            __syncthreads();
        }
        if (t < NBINS) {
            int ex = sm[t] - hv;
            // reserve hv slots in this bin's region (45-sigma overflow headroom)
            int g = atomicAdd(side ? &cur_s[t] : &cur_d[t], hv);
            delta[t] = g - ex;
            lcur[t] = ex;
        }
        __syncthreads();
        if (side == 0) {
            for (int i = t; i < MS_CHUNK; i += 256) {
                int kf = key[e0 + i];
                int v = src[e0 + i];
                int b = kf >> 8;
                int pos = atomicAdd(&lcur[b], 1);
                stage[pos] = ((kf & 255) << 16) | v;   // src < 2^16
                binof[pos] = (unsigned char)b;
            }
            __syncthreads();
            for (int i = t; i < MS_CHUNK; i += 256)
                binned_d[i + delta[binof[i]]] = stage[i];  // ~160B contiguous segments
        } else {
            for (int i = t; i < MS_CHUNK; i += 256) {
                int kf = key[e0 + i];
                int b = kf >> 8;
                int pos = atomicAdd(&lcur[b], 1);
                stage[pos] = kf & 255;
                binof[pos] = (unsigned char)b;
            }
            __syncthreads();
            for (int i = t; i < MS_CHUNK; i += 256)
                binned_s[i + delta[binof[i]]] = (unsigned char)stage[i];
        }
        return;
    }
    if (blockIdx.x == 2 * MS_BLOCKS + 6) {
        int c = t;
        if (c < NCLS) {
            float a0 = 0.f, a1 = 0.f, a2 = 0.f, a3 = 0.f;   // 4 chains for ILP
            for (int k = 0; k < HID; k += 4) {
                a0 += b1[k + 0] * W2[(k + 0) * NCLS + c];
                a1 += b1[k + 1] * W2[(k + 1) * NCLS + c];
                a2 += b1[k + 2] * W2[(k + 2) * NCLS + c];
                a3 += b1[k + 3] * W2[(k + 3) * NCLS + c];
            }
            b1w2[c] = (a0 + a1) + (a2 + a3);
        }
        return;
    }
    // W12 fragment blocks
    float* w2s = (float*)smem;
    for (int i = t; i < HID * NCLS; i += 256) w2s[i] = W2[i];
    __syncthreads();
    int g = (blockIdx.x - 2 * MS_BLOCKS) * 256 + t;   // slot id in [0,1536)
    int kt = g / 192, rem = g % 192;
    int nt = rem >> 6, lane = rem & 63;
    int q = lane >> 4, n = lane & 15;
    int col = nt * 16 + n;
    float acc[8];
#pragma unroll
    for (int j = 0; j < 8; j++) acc[j] = 0.f;
    if (col < NCLS) {
        int k0 = kt * 32 + q * 8;
        const float* w1r = &W1[(size_t)k0 * HID];   // 8 consecutive rows, 16-lane shared
        for (int jj = 0; jj < HID; jj += 4) {
            float w0 = w2s[(jj + 0) * NCLS + col];
            float w1v = w2s[(jj + 1) * NCLS + col];
            float w2v = w2s[(jj + 2) * NCLS + col];
            float w3 = w2s[(jj + 3) * NCLS + col];
#pragma unroll
            for (int j = 0; j < 8; j++) {
                float4 a = *(const float4*)&w1r[j * HID + jj];
                acc[j] += a.x * w0 + a.y * w1v + a.z * w2v + a.w * w3;
            }
        }
    }
    short8 v;
#pragma unroll
    for (int j = 0; j < 8; j++) v[j] = (short)f2bf(acc[j]);
    *(short8*)&w12f[(size_t)g * 8] = v;
}

// per-bin counting sort -> csr16 (gapped regions) + offsets + deg16 + deg^{-1/2}
// dst bins (blocks 0..195); src bins (196..391) -> dout only.

__global__ __launch_bounds__(256) void k_bins(const int* __restrict__ binned_d,
                                              const unsigned char* __restrict__ binned_s,
                                              const int* __restrict__ cur_d,
                                              const int* __restrict__ cur_s,
                                              int* __restrict__ offsets, float* __restrict__ din,
                                              float* __restrict__ dout,
                                              unsigned short* __restrict__ deg16,
                                              unsigned short* __restrict__ csr16) {
    __shared__ int hist[256];
    __shared__ int sm[256];
    __shared__ int cur[256];
    __shared__ int stage[BIN_CAP];
    int t = threadIdx.x;
    hist[t] = 0;
    __syncthreads();
    if (blockIdx.x < NBINS) {
        int bin = blockIdx.x;
        int beg = bin * BIN_CAP;
        int n = cur_d[bin] - beg;       // actual fill of this bin region
        for (int i = t; i < n; i += 256) atomicAdd(&hist[binned_d[beg + i] >> 16], 1);
        __syncthreads();
        int hv = hist[t];
        sm[t] = hv;
        __syncthreads();
        for (int off = 1; off < 256; off <<= 1) {
            int a = (t >= off) ? sm[t - off] : 0;
            __syncthreads();
            sm[t] += a;
            __syncthreads();
        }
        int ex = sm[t] - hv;
        int node = bin * 256 + t;
        if (node < N_NODES) {
            offsets[node] = beg + ex;           // index into gapped csr16
            deg16[node] = (unsigned short)hv;   // per-node degree (gapped layout
            din[node] = hv ? rsqrtf((float)hv) : 0.f;  // breaks offsets[n+1] bound)
        }
        cur[t] = ex;
        __syncthreads();
        for (int i = t; i < n; i += 256) {
            int p = binned_d[beg + i];
            int pos = atomicAdd(&cur[p >> 16], 1);
            if (pos < BIN_CAP) stage[pos] = p & 0xFFFF;
        }
        __syncthreads();
        int m = n < BIN_CAP ? n : BIN_CAP;
        for (int i = t; i < m; i += 256) csr16[beg + i] = (unsigned short)stage[i];
    } else {
        int bin = blockIdx.x - NBINS;
        int beg = bin * BIN_CAP;
        int n = cur_s[bin] - beg;
        for (int i = t; i < n; i += 256) atomicAdd(&hist[binned_s[beg + i]], 1);
        __syncthreads();
        int node = bin * 256 + t;
        if (node < N_NODES) {
            int hv2 = hist[t];
            dout[node] = hv2 ? rsqrtf((float)hv2) : 0.f;
        }
    }
}

// ---------------- GEMM1 (MFMA bf16): g = (x @ W12) * dout[row], 40-wide -------

__global__ __launch_bounds__(256) void k_gemm1(const float* __restrict__ x,
                                               const short* __restrict__ w12f,
                                               const float* __restrict__ dout,
                                               _Float16* __restrict__ gt) {
    int t = threadIdx.x;
    int wv = t >> 6, lane = t & 63;
    int q = lane >> 4, lr = lane & 15;
    int m0 = blockIdx.x * 64 + wv * 16;
    int row = m0 + lr;
    int rowc = min(row, N_NODES - 1);      // clamp: tail rows read row 49999, stores guarded
    v4f acc[3];
#pragma unroll
    for (int n = 0; n < 3; n++) acc[n] = (v4f){0.f, 0.f, 0.f, 0.f};

    const float* xr = &x[(size_t)rowc * IN_F];
#pragma unroll
    for (int kt = 0; kt < 8; kt++) {
        const float4* ap = (const float4*)&xr[kt * 32 + q * 8];
        float4 a0 = ap[0], a1 = ap[1];
        short8 af;
        af[0] = (short)f2bf(a0.x); af[1] = (short)f2bf(a0.y);
        af[2] = (short)f2bf(a0.z); af[3] = (short)f2bf(a0.w);
        af[4] = (short)f2bf(a1.x); af[5] = (short)f2bf(a1.y);
        af[6] = (short)f2bf(a1.z); af[7] = (short)f2bf(a1.w);
#pragma unroll
        for (int nt = 0; nt < 3; nt++) {
            short8 bf = *(const short8*)&w12f[(size_t)((kt * 3 + nt) * 64 + lane) * 8];
            acc[nt] = __builtin_amdgcn_mfma_f32_16x16x32_bf16(af, bf, acc[nt], 0, 0, 0);
        }
    }
    int rbase = m0 + q * 4;
    float4 dv = *(const float4*)&dout[rbase];   // dout is NP-padded, OOB-safe
#pragma unroll
    for (int i = 0; i < 4; i++) {
        int orow = rbase + i;
        if (orow < N_NODES) {
            float s = (i == 0) ? dv.x : (i == 1) ? dv.y : (i == 2) ? dv.z : dv.w;
#pragma unroll
            for (int nt = 0; nt < 3; nt++) {
                int col = nt * 16 + lr;
                if (col < NCLS)
                    gt[(size_t)orow * HS2 + col] = (_Float16)(acc[nt][i] * s);
            }
        }
    }
}

// ---------------- Aggregation 1 (40-wide, dual-half) --------------------------
// Two adjacent dst nodes per wave: lanes 0-31 serve node0, 32-63 node1.
// Ends come from deg16 (gapped csr16 regions); wid0 even -> one uint load
// covers both degrees.

__global__ __launch_bounds__(256) void k_agg1b(const unsigned short* __restrict__ csr16,
                                               const int* __restrict__ offsets,
                                               const unsigned short* __restrict__ deg16,
                                               const _Float16* __restrict__ g,
                                               const float* __restrict__ din,
                                               const float* __restrict__ dout,
                                               const float* __restrict__ b1w2,
                                               _Float16* __restrict__ h2b) {
    int w = (int)((blockIdx.x * 256 + threadIdx.x) >> 6);
    int wid0 = w * 2;
    if (wid0 >= N_NODES) return;
    int wid1 = wid0 + 1;                  // N even -> always valid
    int lane = threadIdx.x & 63;
    int half = lane >> 5;
    int hl = lane & 31;
    int grp = hl >> 3;                    // 4 edge groups per half
    int l = hl & 7;
    bool act = l < 5;                     // 5 lanes x 8 cols = 40
    int colb = min(l, 4) * 8;
    int sbase = half << 5;
    int beg0 = offsets[wid0];
    int beg1 = offsets[wid1];
    unsigned int dp = *(const unsigned int*)&deg16[wid0];
    int end0 = beg0 + (int)(dp & 0xFFFFu);
    int end1 = beg1 + (int)(dp >> 16);
    int myend = half ? end1 : end0;
    h2v a0 = (h2v)0, a1 = (h2v)0, a2 = (h2v)0, a3 = (h2v)0;
    for (int base0 = beg0, base1 = beg1; base0 < end0 || base1 < end1;
         base0 += 32, base1 += 32) {
        int mybase = half ? base1 : base0;
        int idx = mybase + hl;
        int sv = (idx < myend) ? (int)csr16[idx] : 0;
        int mycnt = min(32, myend - mybase);    // uniform per half; may be <= 0
        int mycl = max(mycnt - 1, 0);
        int e0 = grp * 8 + 0, e1 = grp * 8 + 1, e2 = grp * 8 + 2, e3 = grp * 8 + 3;
        int e4 = grp * 8 + 4, e5 = grp * 8 + 5, e6 = grp * 8 + 6, e7 = grp * 8 + 7;
        int s0 = __shfl(sv, sbase + min(e0, mycl));
        int s1 = __shfl(sv, sbase + min(e1, mycl));
        int s2 = __shfl(sv, sbase + min(e2, mycl));
        int s3 = __shfl(sv, sbase + min(e3, mycl));
        int s4 = __shfl(sv, sbase + min(e4, mycl));
        int s5 = __shfl(sv, sbase + min(e5, mycl));
        int s6 = __shfl(sv, sbase + min(e6, mycl));
        int s7 = __shfl(sv, sbase + min(e7, mycl));
        if (act && mycnt > 0) {
            uint4 v0 = *(const uint4*)&g[(size_t)s0 * HS2 + colb];
            uint4 v1 = *(const uint4*)&g[(size_t)s1 * HS2 + colb];
            uint4 v2 = *(const uint4*)&g[(size_t)s2 * HS2 + colb];
            uint4 v3 = *(const uint4*)&g[(size_t)s3 * HS2 + colb];
            uint4 v4 = *(const uint4*)&g[(size_t)s4 * HS2 + colb];
            uint4 v5 = *(const uint4*)&g[(size_t)s5 * HS2 + colb];
            uint4 v6 = *(const uint4*)&g[(size_t)s6 * HS2 + colb];
            uint4 v7 = *(const uint4*)&g[(size_t)s7 * HS2 + colb];
            if (e0 < mycnt) { a0 += u2h(v0.x); a1 += u2h(v0.y); a2 += u2h(v0.z); a3 += u2h(v0.w); }
            if (e1 < mycnt) { a0 += u2h(v1.x); a1 += u2h(v1.y); a2 += u2h(v1.z); a3 += u2h(v1.w); }
            if (e2 < mycnt) { a0 += u2h(v2.x); a1 += u2h(v2.y); a2 += u2h(v2.z); a3 += u2h(v2.w); }
            if (e3 < mycnt) { a0 += u2h(v3.x); a1 += u2h(v3.y); a2 += u2h(v3.z); a3 += u2h(v3.w); }
            if (e4 < mycnt) { a0 += u2h(v4.x); a1 += u2h(v4.y); a2 += u2h(v4.z); a3 += u2h(v4.w); }
            if (e5 < mycnt) { a0 += u2h(v5.x); a1 += u2h(v5.y); a2 += u2h(v5.z); a3 += u2h(v5.w); }
            if (e6 < mycnt) { a0 += u2h(v6.x); a1 += u2h(v6.y); a2 += u2h(v6.z); a3 += u2h(v6.w); }
            if (e7 < mycnt) { a0 += u2h(v7.x); a1 += u2h(v7.y); a2 += u2h(v7.z); a3 += u2h(v7.w); }
        }
    }
    float c[8];
    c[0] = (float)a0[0]; c[1] = (float)a0[1];
    c[2] = (float)a1[0]; c[3] = (float)a1[1];
    c[4] = (float)a2[0]; c[5] = (float)a2[1];
    c[6] = (float)a3[0]; c[7] = (float)a3[1];
#pragma unroll
    for (int i = 0; i < 8; i++) {           // reduce over 4 groups WITHIN half
        c[i] += __shfl_xor(c[i], 8);
        c[i] += __shfl_xor(c[i], 16);
    }
    if (grp == 0 && act) {
        int wid = half ? wid1 : wid0;
        float dd = dout[wid];
        float sc = din[wid] * dd;
        float4 bw0 = *(const float4*)&b1w2[colb];
        float4 bw1 = *(const float4*)&b1w2[colb + 4];
        h2v p0, p1, p2, p3;
        p0[0] = (_Float16)(c[0] * sc + bw0.x * dd); p0[1] = (_Float16)(c[1] * sc + bw0.y * dd);
        p1[0] = (_Float16)(c[2] * sc + bw0.z * dd); p1[1] = (_Float16)(c[3] * sc + bw0.w * dd);
        p2[0] = (_Float16)(c[4] * sc + bw1.x * dd); p2[1] = (_Float16)(c[5] * sc + bw1.y * dd);
        p3[0] = (_Float16)(c[6] * sc + bw1.z * dd); p3[1] = (_Float16)(c[7] * sc + bw1.w * dd);
        uint4 o;
        o.x = h2u(p0); o.y = h2u(p1); o.z = h2u(p2); o.w = h2u(p3);
        *(uint4*)&h2b[(size_t)wid * HS2 + colb] = o;
    }
}

// ---------------- Aggregation 2 + bias + log_softmax (dual-half) --------------

__global__ __launch_bounds__(256) void k_agg2(const unsigned short* __restrict__ csr16,
                                              const int* __restrict__ offsets,
                                              const unsigned short* __restrict__ deg16,
                                              const _Float16* __restrict__ h2b,
                                              const float* __restrict__ din,
                                              const float* __restrict__ b2,
                                              float* __restrict__ out) {
    int w = (int)((blockIdx.x * 256 + threadIdx.x) >> 6);
    int wid0 = w * 2;
    if (wid0 >= N_NODES) return;
    int wid1 = wid0 + 1;
    int lane = threadIdx.x & 63;
    int half = lane >> 5;
    int hl = lane & 31;
    int grp = hl >> 3;
    int l = hl & 7;
    bool act = l < 5;
    int colb = min(l, 4) * 8;
    int sbase = half << 5;
    int beg0 = offsets[wid0];
    int beg1 = offsets[wid1];
    unsigned int dp = *(const unsigned int*)&deg16[wid0];
    int end0 = beg0 + (int)(dp & 0xFFFFu);
    int end1 = beg1 + (int)(dp >> 16);
    int myend = half ? end1 : end0;
    h2v a0 = (h2v)0, a1 = (h2v)0, a2 = (h2v)0, a3 = (h2v)0;
    for (int base0 = beg0, base1 = beg1; base0 < end0 || base1 < end1;
         base0 += 32, base1 += 32) {
        int mybase = half ? base1 : base0;
        int idx = mybase + hl;
        int sv = (idx < myend) ? (int)csr16[idx] : 0;
        int mycnt = min(32, myend - mybase);
        int mycl = max(mycnt - 1, 0);
        int e0 = grp * 8 + 0, e1 = grp * 8 + 1, e2 = grp * 8 + 2, e3 = grp * 8 + 3;
        int e4 = grp * 8 + 4, e5 = grp * 8 + 5, e6 = grp * 8 + 6, e7 = grp * 8 + 7;
        int s0 = __shfl(sv, sbase + min(e0, mycl));
        int s1 = __shfl(sv, sbase + min(e1, mycl));
        int s2 = __shfl(sv, sbase + min(e2, mycl));
        int s3 = __shfl(sv, sbase + min(e3, mycl));
        int s4 = __shfl(sv, sbase + min(e4, mycl));
        int s5 = __shfl(sv, sbase + min(e5, mycl));
        int s6 = __shfl(sv, sbase + min(e6, mycl));
        int s7 = __shfl(sv, sbase + min(e7, mycl));
        if (act && mycnt > 0) {
            uint4 v0 = *(const uint4*)&h2b[(size_t)s0 * HS2 + colb];
            uint4 v1 = *(const uint4*)&h2b[(size_t)s1 * HS2 + colb];
            uint4 v2 = *(const uint4*)&h2b[(size_t)s2 * HS2 + colb];
            uint4 v3 = *(const uint4*)&h2b[(size_t)s3 * HS2 + colb];
            uint4 v4 = *(const uint4*)&h2b[(size_t)s4 * HS2 + colb];
            uint4 v5 = *(const uint4*)&h2b[(size_t)s5 * HS2 + colb];
            uint4 v6 = *(const uint4*)&h2b[(size_t)s6 * HS2 + colb];
            uint4 v7 = *(const uint4*)&h2b[(size_t)s7 * HS2 + colb];
            if (e0 < mycnt) { a0 += u2h(v0.x); a1 += u2h(v0.y); a2 += u2h(v0.z); a3 += u2h(v0.w); }
            if (e1 < mycnt) { a0 += u2h(v1.x); a1 += u2h(v1.y); a2 += u2h(v1.z); a3 += u2h(v1.w); }
            if (e2 < mycnt) { a0 += u2h(v2.x); a1 += u2h(v2.y); a2 += u2h(v2.z); a3 += u2h(v2.w); }
            if (e3 < mycnt) { a0 += u2h(v3.x); a1 += u2h(v3.y); a2 += u2h(v3.z); a3 += u2h(v3.w); }
            if (e4 < mycnt) { a0 += u2h(v4.x); a1 += u2h(v4.y); a2 += u2h(v4.z); a3 += u2h(v4.w); }
            if (e5 < mycnt) { a0 += u2h(v5.x); a1 += u2h(v5.y); a2 += u2h(v5.z); a3 += u2h(v5.w); }
            if (e6 < mycnt) { a0 += u2h(v6.x); a1 += u2h(v6.y); a2 += u2h(v6.z); a3 += u2h(v6.w); }
            if (e7 < mycnt) { a0 += u2h(v7.x); a1 += u2h(v7.y); a2 += u2h(v7.z); a3 += u2h(v7.w); }
        }
    }
    float c[8];
    c[0] = (float)a0[0]; c[1] = (float)a0[1];
    c[2] = (float)a1[0]; c[3] = (float)a1[1];
    c[4] = (float)a2[0]; c[5] = (float)a2[1];
    c[6] = (float)a3[0]; c[7] = (float)a3[1];
#pragma unroll
    for (int i = 0; i < 8; i++) {           // reduce over 4 groups WITHIN half
        c[i] += __shfl_xor(c[i], 8);
        c[i] += __shfl_xor(c[i], 16);
    }
    int wid = half ? wid1 : wid0;
    float sc = din[wid];
    float y[8];
    float lm = -INFINITY;
    if (act) {
        float4 bb0 = *(const float4*)&b2[colb];
        float4 bb1 = *(const float4*)&b2[colb + 4];
        y[0] = c[0] * sc + bb0.x; y[1] = c[1] * sc + bb0.y;
        y[2] = c[2] * sc + bb0.z; y[3] = c[3] * sc + bb0.w;
        y[4] = c[4] * sc + bb1.x; y[5] = c[5] * sc + bb1.y;
        y[6] = c[6] * sc + bb1.z; y[7] = c[7] * sc + bb1.w;
#pragma unroll
        for (int i = 0; i < 8; i++) lm = fmaxf(lm, y[i]);
    }
#pragma unroll
    for (int off = 1; off < 8; off <<= 1) lm = fmaxf(lm, __shfl_xor(lm, off));
    float ls = 0.f;
    if (act) {
#pragma unroll
        for (int i = 0; i < 8; i++) ls += expf(y[i] - lm);
    }
#pragma unroll
    for (int off = 1; off < 8; off <<= 1) ls += __shfl_xor(ls, off);
    if (grp == 0 && act) {
        float lg = logf(ls);
        float4 o0 = make_float4(y[0] - lm - lg, y[1] - lm - lg, y[2] - lm - lg, y[3] - lm - lg);
        float4 o1 = make_float4(y[4] - lm - lg, y[5] - lm - lg, y[6] - lm - lg, y[7] - lm - lg);
        *(float4*)&out[(size_t)wid * NCLS + colb] = o0;
        *(float4*)&out[(size_t)wid * NCLS + colb + 4] = o1;
    }
}

// ---------------- launch ----------------

extern "C" void kernel_launch(void* const* d_in, const int* in_sizes, int n_in,
                              void* d_out, int out_size, void* d_ws, size_t ws_size,
                              hipStream_t stream) {
    const float* x  = (const float*)d_in[0];
    const int* src  = (const int*)d_in[1];
    const int* dst  = (const int*)d_in[2];
    const float* W1 = (const float*)d_in[3];
    const float* b1 = (const float*)d_in[4];
    const float* W2 = (const float*)d_in[5];
    const float* b2 = (const float*)d_in[6];
    float* out = (float*)d_out;

    int* wsi   = (int*)d_ws;
    float* wsf = (float*)d_ws;
    const size_t BINREG = (size_t)NBINS * BIN_CAP;   // 2,408,448 entries per side
    // workspace layout (4B units):
    int* cur_d    = wsi;                      // 256
    int* cur_s    = wsi + 256;                // 256
    float* b1w2   = wsf + 512;                // 40 floats
    int* offsets  = wsi + 1536;               // NP
    float* din    = wsf + 1536 + (size_t)NP;      // NP
    float* dout   = wsf + 1536 + 2 * (size_t)NP;  // NP
    unsigned short* deg16 = (unsigned short*)(wsi + 1536 + 3 * (size_t)NP);  // NP ushorts
    int* binned_d = wsi + 1536 + 3 * (size_t)NP + NP / 2;   // BINREG ints (9.6 MB)
    unsigned char* binned_s = (unsigned char*)(binned_d + BINREG);           // BINREG bytes
    _Float16* gt  = (_Float16*)(binned_s + BINREG);                          // N*HS2 f16 (4.0 MB)
    _Float16* h2b = gt + (size_t)N_NODES * HS2;                              // N*HS2 f16 (4.0 MB)
    short* w12f   = (short*)(h2b + (size_t)N_NODES * HS2);                   // 12288 bf16 (24 KB)
    unsigned short* csr16 = (unsigned short*)(w12f + 12288);                 // BINREG ushorts (4.8 MB)

    k_init<<<1, 256, 0, stream>>>(cur_d, cur_s);
    k_ms<<<2 * MS_BLOCKS + 7, 256, 0, stream>>>(src, dst, cur_d, cur_s, binned_d, binned_s,
                                                W1, b1, W2, w12f, b1w2);
    k_bins<<<2 * NBINS, 256, 0, stream>>>(binned_d, binned_s, cur_d, cur_s,
                                          offsets, din, dout, deg16, csr16);
    k_gemm1<<<(N_NODES + 63) / 64, 256, 0, stream>>>(x, w12f, dout, gt);
    k_agg1b<<<(N_NODES / 2) * 64 / 256, 256, 0, stream>>>(csr16, offsets, deg16, gt, din, dout, b1w2, h2b);
    k_agg2<<<(N_NODES / 2) * 64 / 256, 256, 0, stream>>>(csr16, offsets, deg16, h2b, din, b2, out);
}